// Round 19
// baseline (270.923 us; speedup 1.0000x reference)
//
#include <hip/hip_runtime.h>

// Sparse conv, sorted-message pipeline v14: G=3 k-group chunking for L3
// (Infinity Cache) staging of the msg buffer.
//   r18 (223.8us) pays ~670MB effective DRAM for the msg round-trip
//   (221MB amplified random-128B writes + 226MB reads). Chunking the 27
//   k-offsets into 3 groups shrinks the live msg chunk to 75.5MB -> fits the
//   256MB memory-side MALL (r13's cached-msg failure was at 226MB, thrashing).
//   gemm_g uses CACHED stores; gather_g CACHED loads; chunk is produced and
//   consumed back-to-back so it should never reach DRAM. gather accumulates
//   across groups (g=0 pure write -> replay-safe; d_out compute-only, r17 fix).
//   xw: xcvt x->bf16 | W->frag | zero cnt[G][NVOX]     (~25us)
//   rank: ONE atomic pass, per-group histograms        (~28us)
//   scan1/2/3: G independent in-place exclusive scans  (~8us)
//   per g: gemm_g (MFMA -> cached msg at group-local sorted slot)
//          gather_g (in-lane segment sum, out (+)= partial)

typedef __attribute__((ext_vector_type(8))) short bf16x8;
typedef __attribute__((ext_vector_type(8))) unsigned short u16x8;
typedef __attribute__((ext_vector_type(4))) unsigned short u16x4;
typedef __attribute__((ext_vector_type(4))) float f32x4;
typedef __attribute__((ext_vector_type(2))) float f32x2;

constexpr int KOFF = 27;
constexpr int M = 65536;
constexpr int CIN = 64;
constexpr int COUT = 64;
constexpr int NVOX = 262144;
constexpr int NMSG = KOFF * M;                 // 1,769,472
constexpr int G = 3;
constexpr int KG = KOFF / G;                   // 9
constexpr int MPG = KG * M;                    // 589,824 msgs / group
constexpr int TM_BLOCK = 512;
constexpr int TILES_PER_K = M / TM_BLOCK;      // 128
constexpr int SUBTILES = TM_BLOCK / (4 * 16);  // 8
constexpr int XCVT_BLOCKS = NVOX * CIN / 8 / 256;   // 8192
constexpr int ZERO_BLOCKS = G * NVOX / (256 * 4);   // 768
constexpr int RANK_BPG = MPG / 1024;                // 576 rank-blocks per group

static __device__ __forceinline__ short f2bf(float f) {
  unsigned u = __builtin_bit_cast(unsigned, f);
  unsigned r = (u + 0x7FFFu + ((u >> 16) & 1u)) >> 16;
  return (short)r;
}
static __device__ __forceinline__ float bf2f(unsigned short h) {
  return __builtin_bit_cast(float, (unsigned)h << 16);
}

// -------- xcvt + W-fragment + zero(cnt) --------

__global__ __launch_bounds__(256) void xw_kernel(
    const float* __restrict__ x, const float* __restrict__ W,
    unsigned short* __restrict__ xb, unsigned short* __restrict__ Wf,
    int* __restrict__ starts, int xcvtBlocks) {
  const int b = blockIdx.x;
  if (b < xcvtBlocks) {
    int i = b * 256 + threadIdx.x;
    const float4* p = (const float4*)x + (size_t)i * 2;
    float4 a = p[0], q = p[1];
    u16x8 h;
    h[0] = (unsigned short)f2bf(a.x); h[1] = (unsigned short)f2bf(a.y);
    h[2] = (unsigned short)f2bf(a.z); h[3] = (unsigned short)f2bf(a.w);
    h[4] = (unsigned short)f2bf(q.x); h[5] = (unsigned short)f2bf(q.y);
    h[6] = (unsigned short)f2bf(q.z); h[7] = (unsigned short)f2bf(q.w);
    *(u16x8*)(xb + (size_t)i * 8) = h;
  } else if (b < xcvtBlocks + KOFF) {
    // W[k] -> fragment order: Wf[k][(t*2+u)*64 + l][j] = W[k][u*32+(l>>4)*8+j][t*16+(l&15)]
    int k = b - xcvtBlocks;  // 0..26
    const float* Wk = W + (size_t)k * (CIN * COUT);
    unsigned short* dst = Wf + (size_t)k * 4096;
#pragma unroll
    for (int i = 0; i < 16; ++i) {
      int e = threadIdx.x * 16 + i;
      int j = e & 7, l = (e >> 3) & 63, tu = e >> 9;
      int t = tu >> 1, u = tu & 1;
      dst[e] = (unsigned short)f2bf(Wk[(u * 32 + (l >> 4) * 8 + j) * COUT + t * 16 + (l & 15)]);
    }
  } else {
    int zb = b - xcvtBlocks - KOFF;        // 0..ZERO_BLOCKS-1
    int i = (zb * 256 + threadIdx.x) * 4;  // covers G*NVOX ints
    *(int4*)(starts + i) = make_int4(0, 0, 0, 0);
  }
}

// -------- single atomic pass: per-group rank + histogram --------

__global__ __launch_bounds__(256) void rank_kernel(const int* __restrict__ out_map,
                                                   int* __restrict__ starts,
                                                   int* __restrict__ rank) {
  int g = blockIdx.x / RANK_BPG;                 // blocks never straddle groups
  int* cnt = starts + (size_t)g * NVOX;
  int i = (blockIdx.x * 256 + threadIdx.x) * 4;  // grid = NMSG/1024 = 1728
  int4 om = *(const int4*)(out_map + i);
  int4 rk;
  rk.x = atomicAdd(&cnt[om.x], 1);
  rk.y = atomicAdd(&cnt[om.y], 1);
  rk.z = atomicAdd(&cnt[om.z], 1);
  rk.w = atomicAdd(&cnt[om.w], 1);
  *(int4*)(rank + i) = rk;
}

// -------- G independent in-place scans --------

__global__ __launch_bounds__(256) void scan1_kernel(int* __restrict__ starts,
                                                    int* __restrict__ blockSums) {
  __shared__ int s[256];
  int t = threadIdx.x, i = blockIdx.x * 256 + t;  // grid = G*1024 = 3072
  int c = starts[i];                              // blocks stay within one group
  s[t] = c; __syncthreads();
  for (int off = 1; off < 256; off <<= 1) {
    int add = (t >= off) ? s[t - off] : 0;
    __syncthreads(); s[t] += add; __syncthreads();
  }
  starts[i] = s[t] - c;
  if (t == 255) blockSums[blockIdx.x] = s[t];
}

__global__ __launch_bounds__(256) void scan2_kernel(int* __restrict__ bs) {
  // grid = G; block g exclusive-scans its own 1024 block sums
  __shared__ int s[256];
  int base = blockIdx.x * 1024;
  int t = threadIdx.x;
  int v0 = bs[base+t*4], v1 = bs[base+t*4+1], v2 = bs[base+t*4+2], v3 = bs[base+t*4+3];
  int sum = v0 + v1 + v2 + v3;
  s[t] = sum; __syncthreads();
  for (int off = 1; off < 256; off <<= 1) {
    int add = (t >= off) ? s[t - off] : 0;
    __syncthreads(); s[t] += add; __syncthreads();
  }
  int run = s[t] - sum;
  bs[base+t*4] = run; run += v0;
  bs[base+t*4+1] = run; run += v1;
  bs[base+t*4+2] = run; run += v2;
  bs[base+t*4+3] = run;
}

__global__ __launch_bounds__(256) void scan3_kernel(int* __restrict__ starts,
                                                    const int* __restrict__ blockBase) {
  int i = blockIdx.x * 256 + threadIdx.x;  // grid = G*1024
  starts[i] += blockBase[blockIdx.x];      // group-local segment start
}

// -------- phase A: pipelined GEMM -> CACHED msg at group-local sorted slots ----

template <bool BF16IN>
__global__ __launch_bounds__(256) void gemm_msg_kernel(
    const void* __restrict__ xin, const unsigned short* __restrict__ Wf,
    const int* __restrict__ in_map, const int* __restrict__ out_map,
    const int* __restrict__ rank, const int* __restrict__ gstarts,
    unsigned short* __restrict__ msg, int g) {
  const int k = g * KG + blockIdx.x / TILES_PER_K;  // grid = KG*TILES_PER_K
  const int mblock = (blockIdx.x % TILES_PER_K) * TM_BLOCK;
  const int wave = threadIdx.x >> 6;
  const int l = threadIdx.x & 63;
  const int lg = l >> 4;
  const int lr = l & 15;

  bf16x8 bfrag[4][2];
  const bf16x8* wf = (const bf16x8*)(Wf + (size_t)k * 4096);
#pragma unroll
  for (int t = 0; t < 4; ++t)
#pragma unroll
    for (int u = 0; u < 2; ++u)
      bfrag[t][u] = wf[(t * 2 + u) * 64 + l];

  const int mwave = mblock + wave * (TM_BLOCK / 4);
  const int rb = k * M + mwave;

  auto loadA = [&](int s, bf16x8& A0, bf16x8& A1) {
    int id = in_map[rb + s * 16 + lr];
    if (BF16IN) {
      const unsigned short* xr = (const unsigned short*)xin + (size_t)id * CIN + lg * 8;
      A0 = *(const bf16x8*)(xr);
      A1 = *(const bf16x8*)(xr + 32);
    } else {
      const float* xr = (const float*)xin + (size_t)id * CIN + lg * 8;
      float4 x0 = *(const float4*)(xr);
      float4 x1 = *(const float4*)(xr + 4);
      float4 x2 = *(const float4*)(xr + 32);
      float4 x3 = *(const float4*)(xr + 36);
      A0[0]=f2bf(x0.x); A0[1]=f2bf(x0.y); A0[2]=f2bf(x0.z); A0[3]=f2bf(x0.w);
      A0[4]=f2bf(x1.x); A0[5]=f2bf(x1.y); A0[6]=f2bf(x1.z); A0[7]=f2bf(x1.w);
      A1[0]=f2bf(x2.x); A1[1]=f2bf(x2.y); A1[2]=f2bf(x2.z); A1[3]=f2bf(x2.w);
      A1[4]=f2bf(x3.x); A1[5]=f2bf(x3.y); A1[6]=f2bf(x3.z); A1[7]=f2bf(x3.w);
    }
  };

  int om[4], rk[4];
#pragma unroll
  for (int r = 0; r < 4; ++r) {
    om[r] = out_map[rb + lg * 4 + r];
    rk[r] = rank[rb + lg * 4 + r];
  }

  bf16x8 c0, c1, n0, n1;
  loadA(0, c0, c1);
  loadA(1, n0, n1);

#pragma unroll 1
  for (int s = 0; s < SUBTILES; ++s) {
    bf16x8 p0, p1;
    const bool have = (s + 2 < SUBTILES);
    if (have) loadA(s + 2, p0, p1);

    int omN[4], rkN[4];
    if (s + 1 < SUBTILES) {
      const int rowb = rb + (s + 1) * 16 + lg * 4;
#pragma unroll
      for (int r = 0; r < 4; ++r) { omN[r] = out_map[rowb + r]; rkN[r] = rank[rowb + r]; }
    } else {
#pragma unroll
      for (int r = 0; r < 4; ++r) { omN[r] = 0; rkN[r] = 0; }
    }
    int st[4];
#pragma unroll
    for (int r = 0; r < 4; ++r) st[r] = gstarts[om[r]];

    f32x4 acc[4] = {{0.f,0.f,0.f,0.f},{0.f,0.f,0.f,0.f},{0.f,0.f,0.f,0.f},{0.f,0.f,0.f,0.f}};
#pragma unroll
    for (int t = 0; t < 4; ++t) {
      acc[t] = __builtin_amdgcn_mfma_f32_16x16x32_bf16(c0, bfrag[t][0], acc[t], 0, 0, 0);
      acc[t] = __builtin_amdgcn_mfma_f32_16x16x32_bf16(c1, bfrag[t][1], acc[t], 0, 0, 0);
    }

    // Row layout: position p = lr*4 + t holds channel t*16 + lr.
    // CACHED stores: 75.5MB chunk stays in the memory-side MALL for gather_g.
#pragma unroll
    for (int r = 0; r < 4; ++r) {
      const int sl = st[r] + rk[r];  // group-local slot 0..MPG
      u16x4 h;
      h[0] = (unsigned short)f2bf(acc[0][r]);
      h[1] = (unsigned short)f2bf(acc[1][r]);
      h[2] = (unsigned short)f2bf(acc[2][r]);
      h[3] = (unsigned short)f2bf(acc[3][r]);
      *(u16x4*)(msg + (size_t)sl * 64 + lr * 4) = h;
    }

    c0 = n0; c1 = n1;
    if (have) { n0 = p0; n1 = p1; }
#pragma unroll
    for (int r = 0; r < 4; ++r) { om[r] = omN[r]; rk[r] = rkN[r]; }
  }
}

// -------- phase B: in-lane segment sum; out (+)= partial --------

template <bool ACCUM>
__global__ __launch_bounds__(256) void gather_out_kernel(
    const unsigned short* __restrict__ msg, const int* __restrict__ gstarts,
    float* __restrict__ out) {
  const int wid = (blockIdx.x * 256 + threadIdx.x) >> 6;  // grid = NVOX/32 blocks
  const int p = threadIdx.x & 63;
  const int r = p >> 3;
  const int c = p & 7;
  const int o = wid * 8 + r;

  const int base = gstarts[o];
  const int nxt = (o == NVOX - 1) ? MPG : gstarts[o + 1];
  const int n = nxt - base;
  const unsigned short* src = msg + (size_t)base * 64 + c * 8;

  // CACHED loads: msg chunk is L3-resident from gemm_g's stores.
  u16x8 v[8];
#pragma unroll
  for (int i = 0; i < 8; ++i) {
    int safe = (i < n) ? i : 0;
    v[i] = *(const u16x8*)(src + (size_t)safe * 64);
  }
  float acc[8] = {};
#pragma unroll
  for (int i = 0; i < 8; ++i) {
    float m = (i < n) ? 1.0f : 0.0f;
#pragma unroll
    for (int d = 0; d < 8; ++d)
      acc[d] = fmaf(m, bf2f((unsigned short)v[i][d]), acc[d]);
  }
  for (int i = 8; i < n; ++i) {
    u16x8 t = *(const u16x8*)(src + (size_t)i * 64);
#pragma unroll
    for (int d = 0; d < 8; ++d) acc[d] += bf2f((unsigned short)t[d]);
  }

  // position q = c*8 + d -> channel (d&3)*16 + 2c + (d>>2)
  float* orow = out + (size_t)o * 64 + 2 * c;
  f32x2 s0 = {acc[0], acc[4]};
  f32x2 s1 = {acc[1], acc[5]};
  f32x2 s2 = {acc[2], acc[6]};
  f32x2 s3 = {acc[3], acc[7]};
  if (ACCUM) {  // g>0: out stays L3-hot between passes; g=0 never reads out
    f32x2 q0 = *(f32x2*)(orow);      s0 += q0;
    f32x2 q1 = *(f32x2*)(orow + 16); s1 += q1;
    f32x2 q2 = *(f32x2*)(orow + 32); s2 += q2;
    f32x2 q3 = *(f32x2*)(orow + 48); s3 += q3;
  }
  *(f32x2*)(orow)      = s0;
  *(f32x2*)(orow + 16) = s1;
  *(f32x2*)(orow + 32) = s2;
  *(f32x2*)(orow + 48) = s3;
}

// -------- fallback (atomic scatter) --------

__global__ __launch_bounds__(256) void spconv_atomic_kernel(
    const float* __restrict__ x, const float* __restrict__ W,
    const int* __restrict__ in_map, const int* __restrict__ out_map,
    float* __restrict__ out) {
  const int k = blockIdx.x / TILES_PER_K;
  const int mblock = (blockIdx.x % TILES_PER_K) * TM_BLOCK;
  const int wave = threadIdx.x >> 6;
  const int l = threadIdx.x & 63;
  const int lg = l >> 4;
  const int lr = l & 15;
  bf16x8 bfrag[4][2];
  const float* Wk = W + (size_t)k * (CIN * COUT);
#pragma unroll
  for (int t = 0; t < 4; ++t)
#pragma unroll
    for (int u = 0; u < 2; ++u)
#pragma unroll
      for (int j = 0; j < 8; ++j)
        bfrag[t][u][j] = f2bf(Wk[(u * 32 + lg * 8 + j) * COUT + t * 16 + lr]);
  const int mwave = mblock + wave * (TM_BLOCK / 4);
#pragma unroll 1
  for (int s = 0; s < SUBTILES; ++s) {
    const int mbase = mwave + s * 16;
    const int in_idx = in_map[k * M + mbase + lr];
    const float* xr = x + (size_t)in_idx * CIN + lg * 8;
    float4 x0 = *(const float4*)(xr);
    float4 x1 = *(const float4*)(xr + 4);
    float4 x2 = *(const float4*)(xr + 32);
    float4 x3 = *(const float4*)(xr + 36);
    bf16x8 a0, a1;
    a0[0]=f2bf(x0.x); a0[1]=f2bf(x0.y); a0[2]=f2bf(x0.z); a0[3]=f2bf(x0.w);
    a0[4]=f2bf(x1.x); a0[5]=f2bf(x1.y); a0[6]=f2bf(x1.z); a0[7]=f2bf(x1.w);
    a1[0]=f2bf(x2.x); a1[1]=f2bf(x2.y); a1[2]=f2bf(x2.z); a1[3]=f2bf(x2.w);
    a1[4]=f2bf(x3.x); a1[5]=f2bf(x3.y); a1[6]=f2bf(x3.z); a1[7]=f2bf(x3.w);
    f32x4 acc[4] = {{0.f,0.f,0.f,0.f},{0.f,0.f,0.f,0.f},{0.f,0.f,0.f,0.f},{0.f,0.f,0.f,0.f}};
#pragma unroll
    for (int t = 0; t < 4; ++t) {
      acc[t] = __builtin_amdgcn_mfma_f32_16x16x32_bf16(a0, bfrag[t][0], acc[t], 0, 0, 0);
      acc[t] = __builtin_amdgcn_mfma_f32_16x16x32_bf16(a1, bfrag[t][1], acc[t], 0, 0, 0);
    }
    const int obase = k * M + mbase + lg * 4;
    int oidx[4];
#pragma unroll
    for (int r = 0; r < 4; ++r) oidx[r] = out_map[obase + r];
#pragma unroll
    for (int t = 0; t < 4; ++t)
#pragma unroll
      for (int r = 0; r < 4; ++r)
        atomicAdd(out + (size_t)oidx[r] * COUT + t * 16 + lr, acc[t][r]);
  }
}

extern "C" void kernel_launch(void* const* d_in, const int* in_sizes, int n_in,
                              void* d_out, int out_size, void* d_ws, size_t ws_size,
                              hipStream_t stream) {
  const float* x = (const float*)d_in[0];
  const float* W = (const float*)d_in[1];
  const int* in_map = (const int*)d_in[2];
  const int* out_map = (const int*)d_in[3];
  float* out = (float*)d_out;
  char* ws = (char*)d_ws;

  const size_t msg_b    = (size_t)MPG * 128;         //  75,497,472 (per-group chunk)
  const size_t xb_b     = (size_t)NVOX * CIN * 2;    //  33,554,432
  const size_t rank_b   = (size_t)NMSG * 4;          //   7,077,888
  const size_t wf_b     = (size_t)KOFF * 4096 * 2;   //     221,184
  const size_t starts_b = (size_t)G * NVOX * 4;      //   3,145,728
  const size_t bsum_b   = (size_t)G * 1024 * 4;
  auto pad = [](size_t b) { return (b + 255) & ~(size_t)255; };

  size_t need_p1 = pad(msg_b) + pad(rank_b) + pad(wf_b) + pad(starts_b) + pad(bsum_b);
  size_t need_p0 = need_p1 + pad(xb_b);  // ~119.6 MB
  bool useXb = (ws_size >= need_p0);

  if (ws_size < need_p1) {
    hipMemsetAsync(d_out, 0, (size_t)out_size * sizeof(float), stream);
    spconv_atomic_kernel<<<dim3(KOFF * TILES_PER_K), dim3(256), 0, stream>>>(
        x, W, in_map, out_map, out);
    return;
  }

  size_t off = 0;
  unsigned short* msg = (unsigned short*)(ws + off); off += pad(msg_b);
  unsigned short* xb = nullptr;
  if (useXb) { xb = (unsigned short*)(ws + off); off += pad(xb_b); }
  int* rank = (int*)(ws + off); off += pad(rank_b);
  unsigned short* Wf = (unsigned short*)(ws + off); off += pad(wf_b);
  int* starts = (int*)(ws + off); off += pad(starts_b);
  int* bsum = (int*)(ws + off);

  // xw zeroes starts (compute path); no SDMA, d_out written only by gather.
  int xcvtBlocks = useXb ? XCVT_BLOCKS : 0;
  xw_kernel<<<dim3(xcvtBlocks + KOFF + ZERO_BLOCKS), dim3(256), 0, stream>>>(
      x, W, xb, Wf, starts, xcvtBlocks);

  rank_kernel<<<dim3(NMSG / 1024), dim3(256), 0, stream>>>(out_map, starts, rank);

  scan1_kernel<<<dim3(G * 1024), dim3(256), 0, stream>>>(starts, bsum);
  scan2_kernel<<<dim3(G), dim3(256), 0, stream>>>(bsum);
  scan3_kernel<<<dim3(G * 1024), dim3(256), 0, stream>>>(starts, bsum);

  for (int g = 0; g < G; ++g) {
    const int* gst = starts + (size_t)g * NVOX;
    if (useXb)
      gemm_msg_kernel<true><<<dim3(KG * TILES_PER_K), dim3(256), 0, stream>>>(
          (const void*)xb, Wf, in_map, out_map, rank, gst, msg, g);
    else
      gemm_msg_kernel<false><<<dim3(KG * TILES_PER_K), dim3(256), 0, stream>>>(
          (const void*)x, Wf, in_map, out_map, rank, gst, msg, g);
    if (g == 0)
      gather_out_kernel<false><<<dim3(NVOX / 32), dim3(256), 0, stream>>>(msg, gst, out);
    else
      gather_out_kernel<true><<<dim3(NVOX / 32), dim3(256), 0, stream>>>(msg, gst, out);
  }
}

// Round 20
// 222.536 us; speedup vs baseline: 1.2174x; 1.2174x over previous
//
#include <hip/hip_runtime.h>

// Sparse conv, sorted-message pipeline — r18 configuration RESTORED (measured
// best: 223.8us, replay-safe). r19's G=3 L3-chunking regressed to 270.9
// (rank 72us measured; MALL does not act as a staging buffer under streaming
// writes — third falsification: r13 cached-msg, r12 x-residency, r19 chunk).
//   xw: xcvt x->bf16 | W->MFMA-frag | zero starts (compute path, no SDMA)
//   rank: ONE atomic pass rank[i]=atomicAdd(starts[om],1) (starts -> histogram)
//   scan1/2/3: in-place exclusive prefix on starts + sentinel
//   gemm: dist-2 pipelined xb gather -> bf16 MFMA -> nt msg at starts[om]+rank
//   gather: 8 rows/wave in-lane segment sum, clamped nt loads; SOLE d_out writer

typedef __attribute__((ext_vector_type(8))) short bf16x8;
typedef __attribute__((ext_vector_type(8))) unsigned short u16x8;
typedef __attribute__((ext_vector_type(4))) unsigned short u16x4;
typedef __attribute__((ext_vector_type(4))) float f32x4;
typedef __attribute__((ext_vector_type(2))) float f32x2;

constexpr int KOFF = 27;
constexpr int M = 65536;
constexpr int CIN = 64;
constexpr int COUT = 64;
constexpr int NVOX = 262144;
constexpr int NMSG = KOFF * M;                 // 1,769,472
constexpr int TM_BLOCK = 512;
constexpr int TILES_PER_K = M / TM_BLOCK;      // 128
constexpr int SUBTILES = TM_BLOCK / (4 * 16);  // 8
constexpr int XCVT_BLOCKS = NVOX * CIN / 8 / 256;  // 8192
constexpr int ZERO_BLOCKS = NVOX / (256 * 4);      // 256

static __device__ __forceinline__ short f2bf(float f) {
  unsigned u = __builtin_bit_cast(unsigned, f);
  unsigned r = (u + 0x7FFFu + ((u >> 16) & 1u)) >> 16;
  return (short)r;
}
static __device__ __forceinline__ float bf2f(unsigned short h) {
  return __builtin_bit_cast(float, (unsigned)h << 16);
}

// -------- xcvt + W-fragment + zero(starts) in one launch --------

__global__ __launch_bounds__(256) void xw_kernel(
    const float* __restrict__ x, const float* __restrict__ W,
    unsigned short* __restrict__ xb, unsigned short* __restrict__ Wf,
    int* __restrict__ starts, int xcvtBlocks) {
  const int b = blockIdx.x;
  if (b < xcvtBlocks) {
    int i = b * 256 + threadIdx.x;
    const float4* p = (const float4*)x + (size_t)i * 2;
    float4 a = p[0], q = p[1];
    u16x8 h;
    h[0] = (unsigned short)f2bf(a.x); h[1] = (unsigned short)f2bf(a.y);
    h[2] = (unsigned short)f2bf(a.z); h[3] = (unsigned short)f2bf(a.w);
    h[4] = (unsigned short)f2bf(q.x); h[5] = (unsigned short)f2bf(q.y);
    h[6] = (unsigned short)f2bf(q.z); h[7] = (unsigned short)f2bf(q.w);
    *(u16x8*)(xb + (size_t)i * 8) = h;
  } else if (b < xcvtBlocks + KOFF) {
    // W[k] -> fragment order: Wf[k][(t*2+u)*64 + l][j] = W[k][u*32+(l>>4)*8+j][t*16+(l&15)]
    int k = b - xcvtBlocks;  // 0..26
    const float* Wk = W + (size_t)k * (CIN * COUT);
    unsigned short* dst = Wf + (size_t)k * 4096;
#pragma unroll
    for (int i = 0; i < 16; ++i) {
      int e = threadIdx.x * 16 + i;
      int j = e & 7, l = (e >> 3) & 63, tu = e >> 9;
      int t = tu >> 1, u = tu & 1;
      dst[e] = (unsigned short)f2bf(Wk[(u * 32 + (l >> 4) * 8 + j) * COUT + t * 16 + (l & 15)]);
    }
  } else {
    // zero the starts/histogram buffer (compute path, no SDMA memset)
    int zb = b - xcvtBlocks - KOFF;                    // 0..ZERO_BLOCKS-1
    int i = (zb * 256 + threadIdx.x) * 4;              // covers NVOX ints
    *(int4*)(starts + i) = make_int4(0, 0, 0, 0);
  }
}

// -------- single atomic pass: rank + histogram (into starts) --------

__global__ __launch_bounds__(256) void rank_kernel(const int* __restrict__ out_map,
                                                   int* __restrict__ starts,
                                                   int* __restrict__ rank) {
  int i = (blockIdx.x * 256 + threadIdx.x) * 4;  // grid = NMSG/1024 = 1728
  int4 om = *(const int4*)(out_map + i);
  int4 rk;
  rk.x = atomicAdd(&starts[om.x], 1);
  rk.y = atomicAdd(&starts[om.y], 1);
  rk.z = atomicAdd(&starts[om.z], 1);
  rk.w = atomicAdd(&starts[om.w], 1);
  *(int4*)(rank + i) = rk;
}

// -------- in-place scan: starts (counts) -> exclusive prefix --------

__global__ __launch_bounds__(256) void scan1_kernel(int* __restrict__ starts,
                                                    int* __restrict__ blockSums) {
  __shared__ int s[256];
  int t = threadIdx.x, i = blockIdx.x * 256 + t;  // grid = 1024
  int c = starts[i];
  s[t] = c; __syncthreads();
  for (int off = 1; off < 256; off <<= 1) {
    int add = (t >= off) ? s[t - off] : 0;
    __syncthreads(); s[t] += add; __syncthreads();
  }
  starts[i] = s[t] - c;  // block-local exclusive (in place)
  if (t == 255) blockSums[blockIdx.x] = s[t];
}

__global__ __launch_bounds__(256) void scan2_kernel(int* __restrict__ bs) {
  __shared__ int s[256];
  int t = threadIdx.x;
  int v0 = bs[t*4], v1 = bs[t*4+1], v2 = bs[t*4+2], v3 = bs[t*4+3];
  int sum = v0 + v1 + v2 + v3;
  s[t] = sum; __syncthreads();
  for (int off = 1; off < 256; off <<= 1) {
    int add = (t >= off) ? s[t - off] : 0;
    __syncthreads(); s[t] += add; __syncthreads();
  }
  int run = s[t] - sum;
  bs[t*4] = run; run += v0;
  bs[t*4+1] = run; run += v1;
  bs[t*4+2] = run; run += v2;
  bs[t*4+3] = run;
}

__global__ __launch_bounds__(256) void scan3_kernel(int* __restrict__ starts,
                                                    const int* __restrict__ blockBase) {
  int i = blockIdx.x * 256 + threadIdx.x;  // grid = 1024
  starts[i] += blockBase[blockIdx.x];
  if (i == 0) starts[NVOX] = NMSG;  // sentinel
}

// -------- phase A: pipelined GEMM -> nt msg at sorted slots --------

template <bool BF16IN>
__global__ __launch_bounds__(256) void gemm_msg_kernel(
    const void* __restrict__ xin, const unsigned short* __restrict__ Wf,
    const int* __restrict__ in_map, const int* __restrict__ out_map,
    const int* __restrict__ rank, const int* __restrict__ starts,
    unsigned short* __restrict__ msg) {
  const int k = blockIdx.x / TILES_PER_K;
  const int mblock = (blockIdx.x % TILES_PER_K) * TM_BLOCK;
  const int wave = threadIdx.x >> 6;
  const int l = threadIdx.x & 63;
  const int lg = l >> 4;
  const int lr = l & 15;

  bf16x8 bfrag[4][2];
  const bf16x8* wf = (const bf16x8*)(Wf + (size_t)k * 4096);
#pragma unroll
  for (int t = 0; t < 4; ++t)
#pragma unroll
    for (int u = 0; u < 2; ++u)
      bfrag[t][u] = wf[(t * 2 + u) * 64 + l];

  const int mwave = mblock + wave * (TM_BLOCK / 4);
  const int rb = k * M + mwave;

  auto loadA = [&](int s, bf16x8& A0, bf16x8& A1) {
    int id = in_map[rb + s * 16 + lr];
    if (BF16IN) {
      const unsigned short* xr = (const unsigned short*)xin + (size_t)id * CIN + lg * 8;
      A0 = *(const bf16x8*)(xr);
      A1 = *(const bf16x8*)(xr + 32);
    } else {
      const float* xr = (const float*)xin + (size_t)id * CIN + lg * 8;
      float4 x0 = *(const float4*)(xr);
      float4 x1 = *(const float4*)(xr + 4);
      float4 x2 = *(const float4*)(xr + 32);
      float4 x3 = *(const float4*)(xr + 36);
      A0[0]=f2bf(x0.x); A0[1]=f2bf(x0.y); A0[2]=f2bf(x0.z); A0[3]=f2bf(x0.w);
      A0[4]=f2bf(x1.x); A0[5]=f2bf(x1.y); A0[6]=f2bf(x1.z); A0[7]=f2bf(x1.w);
      A1[0]=f2bf(x2.x); A1[1]=f2bf(x2.y); A1[2]=f2bf(x2.z); A1[3]=f2bf(x2.w);
      A1[4]=f2bf(x3.x); A1[5]=f2bf(x3.y); A1[6]=f2bf(x3.z); A1[7]=f2bf(x3.w);
    }
  };

  int om[4], rk[4];
#pragma unroll
  for (int r = 0; r < 4; ++r) {
    om[r] = out_map[rb + lg * 4 + r];
    rk[r] = rank[rb + lg * 4 + r];
  }

  bf16x8 c0, c1, n0, n1;
  loadA(0, c0, c1);
  loadA(1, n0, n1);

#pragma unroll 1
  for (int s = 0; s < SUBTILES; ++s) {
    bf16x8 p0, p1;
    const bool have = (s + 2 < SUBTILES);
    if (have) loadA(s + 2, p0, p1);

    int omN[4], rkN[4];
    if (s + 1 < SUBTILES) {
      const int rowb = rb + (s + 1) * 16 + lg * 4;
#pragma unroll
      for (int r = 0; r < 4; ++r) { omN[r] = out_map[rowb + r]; rkN[r] = rank[rowb + r]; }
    } else {
#pragma unroll
      for (int r = 0; r < 4; ++r) { omN[r] = 0; rkN[r] = 0; }
    }
    int st[4];
#pragma unroll
    for (int r = 0; r < 4; ++r) st[r] = starts[om[r]];

    f32x4 acc[4] = {{0.f,0.f,0.f,0.f},{0.f,0.f,0.f,0.f},{0.f,0.f,0.f,0.f},{0.f,0.f,0.f,0.f}};
#pragma unroll
    for (int t = 0; t < 4; ++t) {
      acc[t] = __builtin_amdgcn_mfma_f32_16x16x32_bf16(c0, bfrag[t][0], acc[t], 0, 0, 0);
      acc[t] = __builtin_amdgcn_mfma_f32_16x16x32_bf16(c1, bfrag[t][1], acc[t], 0, 0, 0);
    }

    // Row layout: position p = lr*4 + t holds channel t*16 + lr.
#pragma unroll
    for (int r = 0; r < 4; ++r) {
      const int sl = st[r] + rk[r];
      u16x4 h;
      h[0] = (unsigned short)f2bf(acc[0][r]);
      h[1] = (unsigned short)f2bf(acc[1][r]);
      h[2] = (unsigned short)f2bf(acc[2][r]);
      h[3] = (unsigned short)f2bf(acc[3][r]);
      __builtin_nontemporal_store(h, (u16x4*)(msg + (size_t)sl * 64 + lr * 4));
    }

    c0 = n0; c1 = n1;
    if (have) { n0 = p0; n1 = p1; }
#pragma unroll
    for (int r = 0; r < 4; ++r) { om[r] = omN[r]; rk[r] = rkN[r]; }
  }
}

// -------- phase B: in-lane contiguous segment sum (sole writer of d_out) ----

__global__ __launch_bounds__(256) void gather_out_kernel(
    const unsigned short* __restrict__ msg, const int* __restrict__ starts,
    float* __restrict__ out) {
  const int wid = (blockIdx.x * 256 + threadIdx.x) >> 6;  // grid = NVOX/32 blocks
  const int p = threadIdx.x & 63;
  const int r = p >> 3;   // which of this wave's 8 output rows
  const int c = p & 7;    // 16B chunk within the 128B msg row
  const int o = wid * 8 + r;

  const int base = starts[o];
  const int n = starts[o + 1] - base;
  const unsigned short* src = msg + (size_t)base * 64 + c * 8;

  u16x8 v[8];
#pragma unroll
  for (int i = 0; i < 8; ++i) {
    int safe = (i < n) ? i : 0;
    v[i] = __builtin_nontemporal_load((const u16x8*)(src + (size_t)safe * 64));
  }
  float acc[8] = {};
#pragma unroll
  for (int i = 0; i < 8; ++i) {
    float m = (i < n) ? 1.0f : 0.0f;
#pragma unroll
    for (int d = 0; d < 8; ++d)
      acc[d] = fmaf(m, bf2f((unsigned short)v[i][d]), acc[d]);
  }
  for (int i = 8; i < n; ++i) {
    u16x8 t = __builtin_nontemporal_load((const u16x8*)(src + (size_t)i * 64));
#pragma unroll
    for (int d = 0; d < 8; ++d) acc[d] += bf2f((unsigned short)t[d]);
  }

  // position q = c*8 + d -> channel (d&3)*16 + 2c + (d>>2); all 64 lanes store.
  float* orow = out + (size_t)o * 64 + 2 * c;
  f32x2 s0 = {acc[0], acc[4]};
  f32x2 s1 = {acc[1], acc[5]};
  f32x2 s2 = {acc[2], acc[6]};
  f32x2 s3 = {acc[3], acc[7]};
  __builtin_nontemporal_store(s0, (f32x2*)(orow));
  __builtin_nontemporal_store(s1, (f32x2*)(orow + 16));
  __builtin_nontemporal_store(s2, (f32x2*)(orow + 32));
  __builtin_nontemporal_store(s3, (f32x2*)(orow + 48));
}

// -------- fallback (atomic scatter) --------

__global__ __launch_bounds__(256) void spconv_atomic_kernel(
    const float* __restrict__ x, const float* __restrict__ W,
    const int* __restrict__ in_map, const int* __restrict__ out_map,
    float* __restrict__ out) {
  const int k = blockIdx.x / TILES_PER_K;
  const int mblock = (blockIdx.x % TILES_PER_K) * TM_BLOCK;
  const int wave = threadIdx.x >> 6;
  const int l = threadIdx.x & 63;
  const int lg = l >> 4;
  const int lr = l & 15;
  bf16x8 bfrag[4][2];
  const float* Wk = W + (size_t)k * (CIN * COUT);
#pragma unroll
  for (int t = 0; t < 4; ++t)
#pragma unroll
    for (int u = 0; u < 2; ++u)
#pragma unroll
      for (int j = 0; j < 8; ++j)
        bfrag[t][u][j] = f2bf(Wk[(u * 32 + lg * 8 + j) * COUT + t * 16 + lr]);
  const int mwave = mblock + wave * (TM_BLOCK / 4);
#pragma unroll 1
  for (int s = 0; s < SUBTILES; ++s) {
    const int mbase = mwave + s * 16;
    const int in_idx = in_map[k * M + mbase + lr];
    const float* xr = x + (size_t)in_idx * CIN + lg * 8;
    float4 x0 = *(const float4*)(xr);
    float4 x1 = *(const float4*)(xr + 4);
    float4 x2 = *(const float4*)(xr + 32);
    float4 x3 = *(const float4*)(xr + 36);
    bf16x8 a0, a1;
    a0[0]=f2bf(x0.x); a0[1]=f2bf(x0.y); a0[2]=f2bf(x0.z); a0[3]=f2bf(x0.w);
    a0[4]=f2bf(x1.x); a0[5]=f2bf(x1.y); a0[6]=f2bf(x1.z); a0[7]=f2bf(x1.w);
    a1[0]=f2bf(x2.x); a1[1]=f2bf(x2.y); a1[2]=f2bf(x2.z); a1[3]=f2bf(x2.w);
    a1[4]=f2bf(x3.x); a1[5]=f2bf(x3.y); a1[6]=f2bf(x3.z); a1[7]=f2bf(x3.w);
    f32x4 acc[4] = {{0.f,0.f,0.f,0.f},{0.f,0.f,0.f,0.f},{0.f,0.f,0.f,0.f},{0.f,0.f,0.f,0.f}};
#pragma unroll
    for (int t = 0; t < 4; ++t) {
      acc[t] = __builtin_amdgcn_mfma_f32_16x16x32_bf16(a0, bfrag[t][0], acc[t], 0, 0, 0);
      acc[t] = __builtin_amdgcn_mfma_f32_16x16x32_bf16(a1, bfrag[t][1], acc[t], 0, 0, 0);
    }
    const int obase = k * M + mbase + lg * 4;
    int oidx[4];
#pragma unroll
    for (int r = 0; r < 4; ++r) oidx[r] = out_map[obase + r];
#pragma unroll
    for (int t = 0; t < 4; ++t)
#pragma unroll
      for (int r = 0; r < 4; ++r)
        atomicAdd(out + (size_t)oidx[r] * COUT + t * 16 + lr, acc[t][r]);
  }
}

extern "C" void kernel_launch(void* const* d_in, const int* in_sizes, int n_in,
                              void* d_out, int out_size, void* d_ws, size_t ws_size,
                              hipStream_t stream) {
  const float* x = (const float*)d_in[0];
  const float* W = (const float*)d_in[1];
  const int* in_map = (const int*)d_in[2];
  const int* out_map = (const int*)d_in[3];
  float* out = (float*)d_out;
  char* ws = (char*)d_ws;

  const size_t msg_b    = (size_t)NMSG * 128;        // 226,492,416
  const size_t xb_b     = (size_t)NVOX * CIN * 2;    //  33,554,432
  const size_t rank_b   = (size_t)NMSG * 4;          //   7,077,888
  const size_t wf_b     = (size_t)KOFF * 4096 * 2;   //     221,184
  const size_t starts_b = (size_t)(NVOX + 1) * 4;    //   1,048,580
  const size_t bsum_b   = 1024 * 4;
  auto pad = [](size_t b) { return (b + 255) & ~(size_t)255; };

  size_t need_p1 = pad(msg_b) + pad(rank_b) + pad(wf_b) + pad(starts_b) + pad(bsum_b);
  size_t need_p0 = need_p1 + pad(xb_b);  // 268,398,848 B <= 256 MiB ws
  bool useXb = (ws_size >= need_p0);

  if (ws_size < need_p1) {
    hipMemsetAsync(d_out, 0, (size_t)out_size * sizeof(float), stream);
    spconv_atomic_kernel<<<dim3(KOFF * TILES_PER_K), dim3(256), 0, stream>>>(
        x, W, in_map, out_map, out);
    return;
  }

  size_t off = 0;
  unsigned short* msg = (unsigned short*)(ws + off); off += pad(msg_b);
  unsigned short* xb = nullptr;
  if (useXb) { xb = (unsigned short*)(ws + off); off += pad(xb_b); }
  int* rank = (int*)(ws + off); off += pad(rank_b);
  unsigned short* Wf = (unsigned short*)(ws + off); off += pad(wf_b);
  int* starts = (int*)(ws + off); off += pad(starts_b);
  int* bsum = (int*)(ws + off);

  // xw zeroes starts (compute path); no SDMA memset, no d_out scratch.
  int xcvtBlocks = useXb ? XCVT_BLOCKS : 0;
  xw_kernel<<<dim3(xcvtBlocks + KOFF + ZERO_BLOCKS), dim3(256), 0, stream>>>(
      x, W, xb, Wf, starts, xcvtBlocks);

  rank_kernel<<<dim3(NMSG / 1024), dim3(256), 0, stream>>>(out_map, starts, rank);

  scan1_kernel<<<dim3(NVOX / 256), dim3(256), 0, stream>>>(starts, bsum);
  scan2_kernel<<<dim3(1), dim3(256), 0, stream>>>(bsum);
  scan3_kernel<<<dim3(NVOX / 256), dim3(256), 0, stream>>>(starts, bsum);

  if (useXb)
    gemm_msg_kernel<true><<<dim3(KOFF * TILES_PER_K), dim3(256), 0, stream>>>(
        (const void*)xb, Wf, in_map, out_map, rank, starts, msg);
  else
    gemm_msg_kernel<false><<<dim3(KOFF * TILES_PER_K), dim3(256), 0, stream>>>(
        (const void*)x, Wf, in_map, out_map, rank, starts, msg);

  gather_out_kernel<<<dim3(NVOX / 32), dim3(256), 0, stream>>>(msg, starts, out);
}